// Round 3
// baseline (1945.465 us; speedup 1.0000x reference)
//
#include <hip/hip_runtime.h>
#include <hip/hip_bf16.h>
#include <stdint.h>
#include <stddef.h>

typedef __attribute__((ext_vector_type(8))) short short8;
typedef __attribute__((ext_vector_type(4))) float f32x4;
typedef __attribute__((ext_vector_type(4))) unsigned int u32x4;
typedef __attribute__((ext_vector_type(4))) unsigned short u16x4;

#define NB 512
#define NL 128
#define ND 256
#define NO 16
#define NQ2 16     // K-split planes (d-chunks of 16)
#define KS 16      // MFMA k-steps per chunk (512/32)

// ---- static device scratch ----
__device__ __attribute__((aligned(16))) float g_Vb[2][2][NB][ND];                 // 4 MB fp32 carrier
__device__ __attribute__((aligned(16))) unsigned short g_Pc[2][NQ2][2][NB][ND];   // 16 MB bf16 partials
__device__ __attribute__((aligned(16))) short g_Bf[2][NQ2][2][KS][8][64][8];      // 8 MB frag-major B
__device__ __attribute__((aligned(16))) float g_coreT[ND][33][ND];                // 8 MB core^T
__device__ __attribute__((aligned(16))) float g_xr[NB][NL][32];                   // 8 MB packed x
__device__ __attribute__((aligned(16))) short g_BpreOC[8][256][64][8];
__device__ __attribute__((aligned(16))) float g_Rf[NB][ND];
__device__ __attribute__((aligned(16))) short g_Lh[NB][ND];
__device__ __attribute__((aligned(16))) short g_Ll[NB][ND];
__device__ __attribute__((aligned(16))) float g_T[NB][NO*ND];
__device__ unsigned int g_sync[8];

__device__ inline unsigned short bf16_rne(float f){
  unsigned int u = __float_as_uint(f);
  return (unsigned short)((u + 0x7FFFu + ((u >> 16) & 1u)) >> 16);
}
__device__ inline float b2f(unsigned short u){
  return __uint_as_float((unsigned int)u << 16);
}
__device__ inline unsigned short f2bf(float f){
  __hip_bfloat16 h = __float2bfloat16(f);
  unsigned short u; __builtin_memcpy(&u, &h, 2); return u;
}
__device__ inline unsigned int pk2(float a, float b){
  __hip_bfloat162 h = __float22bfloat162_rn(make_float2(a, b));
  unsigned int u; __builtin_memcpy(&u, &h, 4); return u;
}
__device__ inline f32x4 z4(){ f32x4 v; v[0]=0.f; v[1]=0.f; v[2]=0.f; v[3]=0.f; return v; }

__device__ inline short8 genA(float vm, const f32x4 xa, const f32x4 xb){
  u32x4 u;
  u[0] = pk2(vm*xa[0], vm*xa[1]);
  u[1] = pk2(vm*xa[2], vm*xa[3]);
  u[2] = pk2(vm*xb[0], vm*xb[1]);
  u[3] = pk2(vm*xb[2], vm*xb[3]);
  return __builtin_bit_cast(short8, u);
}

// ---- core^T (tiled, coalesced): g_coreT[e][f][d] = core[d][f][e] ----
__global__ void k_coreT(const float* __restrict__ core){
  const int bid = blockIdx.x;            // 33*8*8 = 2112
  const int f  = bid % 33;
  const int dt = (bid / 33) & 7;
  const int et = bid / 264;
  __shared__ float tile[32][33];
  const int j  = threadIdx.x & 31;
  const int i0 = threadIdx.x >> 5;
  #pragma unroll
  for (int ii = 0; ii < 4; ii++){
    const int i = i0*4 + ii;
    tile[i][j] = core[((size_t)(dt*32 + i)*33 + f)*256 + et*32 + j];
  }
  __syncthreads();
  #pragma unroll
  for (int ii = 0; ii < 4; ii++){
    const int i = i0*4 + ii;
    g_coreT[et*32 + i][f][dt*32 + j] = tile[j][i];
  }
}

// ---- fragment-major B, both dirs (coalesced via core / coreT) ----
__global__ void k_bf(const float* __restrict__ core){
  const int id = blockIdx.x*512 + threadIdx.x;   // 1024 blocks -> 524288
  const int l   = id & 63;
  const int nf  = (id >> 6) & 7;
  const int ks  = (id >> 9) & 15;
  const int nt  = (id >> 13) & 1;
  const int kq  = (id >> 14) & 15;
  const int dir = id >> 18;
  const float* src = dir ? &g_coreT[0][0][0] : core;
  const int n_g = nt*128 + nf*16 + (l & 15);
  const int dl  = kq*16 + ks;
  short8 v;
  #pragma unroll
  for (int i = 0; i < 8; i++){
    const int f = (l >> 4)*8 + i + 1;
    v[i] = (short)bf16_rne(src[((size_t)dl*33 + f)*256 + n_g]);
  }
  *(short8*)&g_Bf[dir][kq][nt][ks][nf][l][0] = v;
}

// ---- fragment-major output_core ----
__global__ void k_bpreoc(const float* __restrict__ oc){
  const int id = blockIdx.x*256 + threadIdx.x;  // 512 blocks
  const int l = id & 63;
  const int nfrag = (id >> 6) & 255;
  const int ks = id >> 14;
  const int g = l >> 4;
  short8 v;
  #pragma unroll
  for (int i = 0; i < 8; i++){
    const int d = ks*32 + g*8 + i;
    v[i] = (short)bf16_rne(oc[(size_t)d*4096 + nfrag*16 + (l & 15)]);
  }
  *(short8*)&g_BpreOC[ks][nfrag][l][0] = v;
}

// ---- repack inputs, dropping bias channel ----
__global__ void k_xr(const float* __restrict__ inputs){
  const int id = blockIdx.x*256 + threadIdx.x;  // 2048 blocks
  const int j = id & 7;
  const int pos = (id >> 3) & 127;
  const int b = id >> 10;
  const float* src = inputs + ((size_t)b*128 + pos)*33 + 1 + j*4;
  f32x4 v; v[0]=src[0]; v[1]=src[1]; v[2]=src[2]; v[3]=src[3];
  *(f32x4*)&g_xr[b][pos][j*4] = v;
}

// ---- init: Pc[0]=0, Vb[0]=alpha/omega, sync=0 ----
__global__ void k_init(const float* __restrict__ alpha, const float* __restrict__ omega){
  const int id = blockIdx.x*512 + threadIdx.x;  // 1024 blocks -> 524288
  short8 z;
  #pragma unroll
  for (int i = 0; i < 8; i++) z[i] = 0;
  ((short8*)&g_Pc[0][0][0][0][0])[id] = z;      // 16*2*512*256/8 = 524288
  if (id < 262144){
    const int n = id & 255;
    const int b = (id >> 8) & 511;
    const int dir = id >> 17;
    g_Vb[0][dir][b][n] = dir ? omega[n] : alpha[n];
  }
  if (id < 8) g_sync[id] = 0;
}

// ---- persistent chain kernel: all 64 steps, group barrier between ----
__global__ void __launch_bounds__(512, 1) k_chain(int nsteps){
  extern __shared__ char lds[];
  short* Bl = (short*)lds;                      // [16 ks][8 nf][64][8] = 128 KB
  float* Vl = (float*)(lds + 131072);           // [16][132] = 8448 B

  const int bid = blockIdx.x;                   // 256
  const int dir = bid & 1;
  const int bt  = (bid >> 1) & 3;
  const int r   = bid >> 3;
  const int kq  = r & 15;
  const int nt  = r >> 4;
  const int grp = bid & 7;                      // (dir,bt): 32 blocks/group, XCD-local

  const int t = threadIdx.x;
  const int lane = t & 63, w = t >> 6;
  const int wm = w & 3, wn = w >> 2;            // wave tile 32 m x 64 n

  // one-time: B slice -> LDS (consumed after first in-loop barrier)
  {
    const short8* src = (const short8*)&g_Bf[dir][kq][nt][0][0][0][0];
    short8* dst = (short8*)Bl;
    #pragma unroll
    for (int it = 0; it < 16; it++)
      dst[it*512 + t] = src[it*512 + t];
  }

  const int m_s   = t >> 2;                     // staging row 0..127
  const int dg    = t & 3;                      // 4 d's each
  const int row_s = bt*128 + m_s;
  const int ml0   = wm*32 + (lane & 15);        // mi adds +16
  const int row0  = bt*128 + ml0;
  const int g     = lane >> 4;
  const short8* Bw = ((const short8*)Bl) + (wn*4)*64 + lane;

  for (int s = 0; s < nsteps; s++){
    const int pp = s & 1, np = pp ^ 1;
    const int pos = dir ? (127 - s) : s;

    // ---- staging: V = Vb + sum of 16 bf16 partials; carry Vb (nt==0) ----
    {
      f32x4 v = *(const f32x4*)&g_Vb[pp][dir][row_s][kq*16 + dg*4];
      const unsigned short* pc = &g_Pc[pp][0][dir][row_s][kq*16 + dg*4];
      #pragma unroll
      for (int q = 0; q < NQ2; q++){
        u16x4 c = *(const u16x4*)(pc + (size_t)q * (2*NB*ND));
        v[0] += b2f(c[0]); v[1] += b2f(c[1]); v[2] += b2f(c[2]); v[3] += b2f(c[3]);
      }
      #pragma unroll
      for (int j = 0; j < 4; j++) Vl[(dg*4 + j)*132 + m_s] = v[j];
      if (nt == 0) *(f32x4*)&g_Vb[np][dir][row_s][kq*16 + dg*4] = v;
    }
    // x slices (global, overlap with staging latency)
    const f32x4 xa0 = *(const f32x4*)&g_xr[row0][pos][g*8];
    const f32x4 xb0 = *(const f32x4*)&g_xr[row0][pos][g*8 + 4];
    const f32x4 xa1 = *(const f32x4*)&g_xr[row0 + 16][pos][g*8];
    const f32x4 xb1 = *(const f32x4*)&g_xr[row0 + 16][pos][g*8 + 4];

    __syncthreads();   // Vl ready (and Bl on s==0)

    f32x4 ac0[4] = { z4(), z4(), z4(), z4() };
    f32x4 ac1[4] = { z4(), z4(), z4(), z4() };
    #pragma unroll 4
    for (int ks = 0; ks < KS; ks++){
      const float va = Vl[ks*132 + ml0];
      const float vb = Vl[ks*132 + ml0 + 16];
      short8 b0 = Bw[(ks*8 + 0)*64];
      short8 b1 = Bw[(ks*8 + 1)*64];
      short8 b2 = Bw[(ks*8 + 2)*64];
      short8 b3 = Bw[(ks*8 + 3)*64];
      const short8 a0 = genA(va, xa0, xb0);
      ac0[0] = __builtin_amdgcn_mfma_f32_16x16x32_bf16(a0, b0, ac0[0], 0, 0, 0);
      ac0[1] = __builtin_amdgcn_mfma_f32_16x16x32_bf16(a0, b1, ac0[1], 0, 0, 0);
      ac0[2] = __builtin_amdgcn_mfma_f32_16x16x32_bf16(a0, b2, ac0[2], 0, 0, 0);
      ac0[3] = __builtin_amdgcn_mfma_f32_16x16x32_bf16(a0, b3, ac0[3], 0, 0, 0);
      const short8 a1 = genA(vb, xa1, xb1);
      ac1[0] = __builtin_amdgcn_mfma_f32_16x16x32_bf16(a1, b0, ac1[0], 0, 0, 0);
      ac1[1] = __builtin_amdgcn_mfma_f32_16x16x32_bf16(a1, b1, ac1[1], 0, 0, 0);
      ac1[2] = __builtin_amdgcn_mfma_f32_16x16x32_bf16(a1, b2, ac1[2], 0, 0, 0);
      ac1[3] = __builtin_amdgcn_mfma_f32_16x16x32_bf16(a1, b3, ac1[3], 0, 0, 0);
    }

    // ---- write bf16 correction partials ----
    {
      const int row_o0 = bt*128 + wm*32 + ((lane >> 4) << 2);
      const int n_o0 = nt*128 + wn*64 + (lane & 15);
      #pragma unroll
      for (int ni = 0; ni < 4; ni++){
        #pragma unroll
        for (int rr = 0; rr < 4; rr++){
          g_Pc[np][kq][dir][row_o0 + rr][n_o0 + ni*16]      = f2bf(ac0[ni][rr]);
          g_Pc[np][kq][dir][row_o0 + 16 + rr][n_o0 + ni*16] = f2bf(ac1[ni][rr]);
        }
      }
    }

    // ---- device-scope group barrier (32 blocks sharing (dir,bt)) ----
    __syncthreads();                       // all stores drained (vmcnt 0 per wave)
    if (t == 0){
      __threadfence();                     // agent release: L2 writeback for cross-XCD
      __hip_atomic_fetch_add(&g_sync[grp], 1u, __ATOMIC_RELAXED, __HIP_MEMORY_SCOPE_AGENT);
      const unsigned int target = 32u * (unsigned)(s + 1);
      while (__hip_atomic_load(&g_sync[grp], __ATOMIC_RELAXED, __HIP_MEMORY_SCOPE_AGENT) < target)
        __builtin_amdgcn_s_sleep(2);
      __threadfence();                     // agent acquire: invalidate stale L1/L2
    }
    __syncthreads();
  }
}

// ---- final boundary vectors; L split hi/lo bf16 ----
__global__ void k_lr(){
  const int id = blockIdx.x*256 + threadIdx.x;  // 1024 blocks
  const int n = id & 255;
  const int b = (id >> 8) & 511;
  const int dir = id >> 17;
  float s = g_Vb[0][dir][b][n];
  #pragma unroll
  for (int q = 0; q < NQ2; q++) s += b2f(g_Pc[0][q][dir][b][n]);
  if (dir == 0){
    const unsigned int u = __float_as_uint(s);
    g_Lh[b][n] = (short)(u >> 16);
    const float rr = s - __uint_as_float(u & 0xFFFF0000u);
    g_Ll[b][n] = (short)(__float_as_uint(rr) >> 16);
  } else {
    g_Rf[b][n] = s;
  }
}

// ---- T[b,(o,e)] = sum_d L[b,d] * oc[d,(o,e)] ----
__launch_bounds__(512, 1)
__global__ void k_gemm1(){
  const int bt = blockIdx.x >> 5;
  const int nt = blockIdx.x & 31;
  const int t = threadIdx.x, lane = t & 63;
  const int w = t >> 6, wm = w >> 2, wn = w & 3;
  f32x4 acc[4][2];
  #pragma unroll
  for (int i = 0; i < 4; i++)
    #pragma unroll
    for (int j = 0; j < 2; j++) acc[i][j] = z4();
  #pragma unroll
  for (int ks = 0; ks < 8; ks++){
    short8 bfr[2];
    #pragma unroll
    for (int ni = 0; ni < 2; ni++)
      bfr[ni] = *(const short8*)&g_BpreOC[ks][nt*8 + wn*2 + ni][lane][0];
    const int k0 = ks*32 + (lane >> 4)*8;
    #pragma unroll
    for (int mi = 0; mi < 4; mi++){
      const int bm = bt*128 + wm*64 + mi*16 + (lane & 15);
      const short8 ah = *(const short8*)&g_Lh[bm][k0];
      const short8 al = *(const short8*)&g_Ll[bm][k0];
      #pragma unroll
      for (int ni = 0; ni < 2; ni++){
        acc[mi][ni] = __builtin_amdgcn_mfma_f32_16x16x32_bf16(ah, bfr[ni], acc[mi][ni], 0, 0, 0);
        acc[mi][ni] = __builtin_amdgcn_mfma_f32_16x16x32_bf16(al, bfr[ni], acc[mi][ni], 0, 0, 0);
      }
    }
  }
  #pragma unroll
  for (int mi = 0; mi < 4; mi++){
    const int row0 = bt*128 + wm*64 + mi*16 + ((lane >> 4) << 2);
    #pragma unroll
    for (int ni = 0; ni < 2; ni++){
      const int n = nt*128 + wn*32 + ni*16 + (lane & 15);
      #pragma unroll
      for (int r = 0; r < 4; r++) g_T[row0 + r][n] = acc[mi][ni][r];
    }
  }
}

// ---- out[b,o] = sum_e T[b,(o,e)] * R[b,e] ----
__global__ void k_out(float* __restrict__ out){
  const int b0 = blockIdx.x * 8;    // 64 blocks
  __shared__ float Rl[8][256];
  const int t = threadIdx.x;
  for (int i = t; i < 2048; i += 256)
    Rl[i >> 8][i & 255] = g_Rf[b0 + (i >> 8)][i & 255];
  __syncthreads();
  const int bl = t >> 5;
  const int o  = (t >> 1) & 15;
  const int eh = t & 1;
  const float* Trow = &g_T[b0 + bl][o*256 + eh*128];
  const float* Rr = &Rl[bl][eh*128];
  float acc = 0.f;
  #pragma unroll 8
  for (int e4 = 0; e4 < 32; e4++){
    const f32x4 tv = *(const f32x4*)(Trow + e4*4);
    const f32x4 rv = *(const f32x4*)(Rr + e4*4);
    acc += tv[0]*rv[0] + tv[1]*rv[1] + tv[2]*rv[2] + tv[3]*rv[3];
  }
  acc += __shfl_xor(acc, 1);
  if (eh == 0) out[(b0 + bl)*16 + o] = acc;
}

extern "C" void kernel_launch(void* const* d_in, const int* in_sizes, int n_in,
                              void* d_out, int out_size, void* d_ws, size_t ws_size,
                              hipStream_t stream){
  const float* inputs = (const float*)d_in[0];
  const float* core   = (const float*)d_in[1];
  const float* alpha  = (const float*)d_in[2];
  const float* omega  = (const float*)d_in[3];
  const float* oc     = (const float*)d_in[4];
  float* out = (float*)d_out;
  (void)in_sizes; (void)n_in; (void)out_size; (void)d_ws; (void)ws_size;

  k_coreT <<<dim3(2112), dim3(256), 0, stream>>>(core);
  k_bf    <<<dim3(1024), dim3(512), 0, stream>>>(core);
  k_bpreoc<<<dim3(512),  dim3(256), 0, stream>>>(oc);
  k_xr    <<<dim3(2048), dim3(256), 0, stream>>>(inputs);
  k_init  <<<dim3(1024), dim3(512), 0, stream>>>(alpha, omega);

  const unsigned int ldsBytes = 131072 + 16*132*4;  // 139520
  hipFuncSetAttribute((const void*)k_chain,
                      hipFuncAttributeMaxDynamicSharedMemorySize, (int)ldsBytes);
  int nsteps = 64;
  void* args[] = { &nsteps };
  hipLaunchCooperativeKernel((const void*)k_chain, dim3(256), dim3(512),
                             args, ldsBytes, stream);

  k_lr    <<<dim3(1024), dim3(256), 0, stream>>>();
  k_gemm1 <<<dim3(128),  dim3(512), 0, stream>>>();
  k_out   <<<dim3(64),   dim3(256), 0, stream>>>(out);
}

// Round 5
// 713.274 us; speedup vs baseline: 2.7275x; 2.7275x over previous
//
#include <hip/hip_runtime.h>
#include <hip/hip_bf16.h>
#include <stdint.h>
#include <stddef.h>

typedef __attribute__((ext_vector_type(8))) short short8;
typedef __attribute__((ext_vector_type(4))) float f32x4;
typedef __attribute__((ext_vector_type(2))) float f32x2;
typedef __attribute__((ext_vector_type(4))) unsigned int u32x4;
typedef __attribute__((ext_vector_type(4))) unsigned short u16x4;

#define NB 512
#define NL 128
#define ND 256
#define NO 16
#define NQ2 16     // K-split planes (d-chunks of 16)
#define KS 16      // MFMA k-steps per chunk

// ---- static device scratch ----
// u64-typed so 8B __hip_atomic_* ops have provable natural alignment.
__device__ __attribute__((aligned(16))) unsigned long long g_Vb[2][2][NB][ND/2];     // fp32 carrier (2 floats/elem)
__device__ __attribute__((aligned(16))) unsigned long long g_Pc[2][NQ2][2][NB][ND/4]; // bf16 partials (4 shorts/elem)
__device__ __attribute__((aligned(16))) short g_Bf[2][NQ2][2][KS][8][64][8];          // frag-major B
__device__ __attribute__((aligned(16))) float g_coreT[ND][33][ND];                    // core^T
__device__ __attribute__((aligned(16))) float g_xr[NB][NL][32];                       // packed x
__device__ __attribute__((aligned(16))) short g_BpreOC[8][256][64][8];
__device__ __attribute__((aligned(16))) float g_Rf[NB][ND];
__device__ __attribute__((aligned(16))) short g_Lh[NB][ND];
__device__ __attribute__((aligned(16))) short g_Ll[NB][ND];
__device__ __attribute__((aligned(16))) float g_T[NB][NO*ND];
__device__ __attribute__((aligned(256))) unsigned int g_sync[8][64];  // padded counters

__device__ inline unsigned short bf16_rne(float f){
  unsigned int u = __float_as_uint(f);
  return (unsigned short)((u + 0x7FFFu + ((u >> 16) & 1u)) >> 16);
}
__device__ inline float b2f(unsigned short u){
  return __uint_as_float((unsigned int)u << 16);
}
__device__ inline unsigned short f2bf(float f){
  __hip_bfloat16 h = __float2bfloat16(f);
  unsigned short u; __builtin_memcpy(&u, &h, 2); return u;
}
__device__ inline unsigned int pk2(float a, float b){
  __hip_bfloat162 h = __float22bfloat162_rn(make_float2(a, b));
  unsigned int u; __builtin_memcpy(&u, &h, 4); return u;
}
__device__ inline f32x4 z4(){ f32x4 v; v[0]=0.f; v[1]=0.f; v[2]=0.f; v[3]=0.f; return v; }

__device__ inline short8 genA(float vm, const f32x4 xa, const f32x4 xb){
  u32x4 u;
  u[0] = pk2(vm*xa[0], vm*xa[1]);
  u[1] = pk2(vm*xa[2], vm*xa[3]);
  u[2] = pk2(vm*xb[0], vm*xb[1]);
  u[3] = pk2(vm*xb[2], vm*xb[3]);
  return __builtin_bit_cast(short8, u);
}

// ---- core^T (tiled, coalesced): g_coreT[e][f][d] = core[d][f][e] ----
__global__ void k_coreT(const float* __restrict__ core){
  const int bid = blockIdx.x;            // 2112
  const int f  = bid % 33;
  const int dt = (bid / 33) & 7;
  const int et = bid / 264;
  __shared__ float tile[32][33];
  const int j  = threadIdx.x & 31;
  const int i0 = threadIdx.x >> 5;
  #pragma unroll
  for (int ii = 0; ii < 4; ii++){
    const int i = i0*4 + ii;
    tile[i][j] = core[((size_t)(dt*32 + i)*33 + f)*256 + et*32 + j];
  }
  __syncthreads();
  #pragma unroll
  for (int ii = 0; ii < 4; ii++){
    const int i = i0*4 + ii;
    g_coreT[et*32 + i][f][dt*32 + j] = tile[j][i];
  }
}

// ---- fragment-major B, both dirs; ni-interleaved column permutation ----
// fragment nf holds logical column (nf&~3)*16 + (l&15)*4 + (nf&3)
__global__ void k_bf(const float* __restrict__ core){
  const int id = blockIdx.x*512 + threadIdx.x;   // 1024 blocks
  const int l   = id & 63;
  const int nf  = (id >> 6) & 7;
  const int ks  = (id >> 9) & 15;
  const int nt  = (id >> 13) & 1;
  const int kq  = (id >> 14) & 15;
  const int dir = id >> 18;
  const float* src = dir ? &g_coreT[0][0][0] : core;
  const int n_g = nt*128 + (nf >> 2)*64 + (l & 15)*4 + (nf & 3);
  const int dl  = kq*16 + ks;
  short8 v;
  #pragma unroll
  for (int i = 0; i < 8; i++){
    const int f = (l >> 4)*8 + i + 1;
    v[i] = (short)bf16_rne(src[((size_t)dl*33 + f)*256 + n_g]);
  }
  *(short8*)&g_Bf[dir][kq][nt][ks][nf][l][0] = v;
}

// ---- fragment-major output_core ----
__global__ void k_bpreoc(const float* __restrict__ oc){
  const int id = blockIdx.x*256 + threadIdx.x;  // 512 blocks
  const int l = id & 63;
  const int nfrag = (id >> 6) & 255;
  const int ks = id >> 14;
  const int g = l >> 4;
  short8 v;
  #pragma unroll
  for (int i = 0; i < 8; i++){
    const int d = ks*32 + g*8 + i;
    v[i] = (short)bf16_rne(oc[(size_t)d*4096 + nfrag*16 + (l & 15)]);
  }
  *(short8*)&g_BpreOC[ks][nfrag][l][0] = v;
}

// ---- repack inputs, dropping bias channel ----
__global__ void k_xr(const float* __restrict__ inputs){
  const int id = blockIdx.x*256 + threadIdx.x;  // 2048 blocks
  const int j = id & 7;
  const int pos = (id >> 3) & 127;
  const int b = id >> 10;
  const float* src = inputs + ((size_t)b*128 + pos)*33 + 1 + j*4;
  f32x4 v; v[0]=src[0]; v[1]=src[1]; v[2]=src[2]; v[3]=src[3];
  *(f32x4*)&g_xr[b][pos][j*4] = v;
}

// ---- init: Vb[0] = alpha/omega, sync = 0 (Pc[0] not needed: s==0 skips it) ----
__global__ void k_init(const float* __restrict__ alpha, const float* __restrict__ omega){
  const int id = blockIdx.x*512 + threadIdx.x;  // 256 blocks -> 131072 u64 elems
  const int n2 = id & 127;
  const int b = (id >> 7) & 511;
  const int dir = id >> 16;
  const float* src = dir ? omega : alpha;
  f32x2 v; v[0] = src[n2*2]; v[1] = src[n2*2 + 1];
  g_Vb[0][dir][b][n2] = __builtin_bit_cast(unsigned long long, v);
  if (id < 512) ((unsigned int*)g_sync)[id] = 0;
}

// ---- persistent chain kernel: fenceless device-coherent communication ----
__global__ void __launch_bounds__(512, 1) k_chain(int nsteps){
  extern __shared__ char lds[];
  short* Bl = (short*)lds;                      // [16 ks][8 nf][64][8] = 128 KB
  float* Vl = (float*)(lds + 131072);           // [16][132]

  const int bid = blockIdx.x;                   // 256
  const int dir = bid & 1;
  const int bt  = (bid >> 1) & 3;
  const int r   = bid >> 3;
  const int kq  = r & 15;
  const int nt  = r >> 4;
  const int grp = bid & 7;                      // (dir,bt) group of 32 blocks

  const int t = threadIdx.x;
  const int lane = t & 63, w = t >> 6;
  const int wm = w & 3, wn = w >> 2;

  // one-time: B slice -> LDS
  {
    const short8* src = (const short8*)&g_Bf[dir][kq][nt][0][0][0][0];
    short8* dst = (short8*)Bl;
    #pragma unroll
    for (int it = 0; it < 16; it++)
      dst[it*512 + t] = src[it*512 + t];
  }

  const int m_s   = t >> 2;
  const int dg    = t & 3;
  const int row_s = bt*128 + m_s;
  const int vb_i  = (kq*16 + dg*4) >> 1;        // u64 index into Vb row
  const int pc_i  = kq*4 + dg;                  // u64 index into Pc row
  const int ml0   = wm*32 + (lane & 15);
  const int row0  = bt*128 + ml0;
  const int g     = lane >> 4;
  const short8* Bw = ((const short8*)Bl) + (wn*4)*64 + lane;

  for (int s = 0; s < nsteps; s++){
    const int pp = s & 1, np = pp ^ 1;
    const int pos = dir ? (127 - s) : s;

    // ---- staging: V = Vb + sum of 16 bf16 partials (device-scope loads) ----
    {
      unsigned long long vb0 = __hip_atomic_load(&g_Vb[pp][dir][row_s][vb_i],
        __ATOMIC_RELAXED, __HIP_MEMORY_SCOPE_AGENT);
      unsigned long long vb1 = __hip_atomic_load(&g_Vb[pp][dir][row_s][vb_i + 1],
        __ATOMIC_RELAXED, __HIP_MEMORY_SCOPE_AGENT);
      f32x2 a = __builtin_bit_cast(f32x2, vb0);
      f32x2 b = __builtin_bit_cast(f32x2, vb1);
      f32x4 v; v[0]=a[0]; v[1]=a[1]; v[2]=b[0]; v[3]=b[1];
      if (s > 0){
        unsigned long long cs[NQ2];
        const unsigned long long* pc = &g_Pc[pp][0][dir][row_s][pc_i];
        #pragma unroll
        for (int q = 0; q < NQ2; q++)
          cs[q] = __hip_atomic_load(pc + (size_t)q * (2*NB*(ND/4)),
            __ATOMIC_RELAXED, __HIP_MEMORY_SCOPE_AGENT);
        #pragma unroll
        for (int q = 0; q < NQ2; q++){
          u16x4 c = __builtin_bit_cast(u16x4, cs[q]);
          v[0] += b2f(c[0]); v[1] += b2f(c[1]); v[2] += b2f(c[2]); v[3] += b2f(c[3]);
        }
      }
      #pragma unroll
      for (int j = 0; j < 4; j++) Vl[(dg*4 + j)*132 + m_s] = v[j];
      if (nt == 0){
        f32x2 s0; s0[0]=v[0]; s0[1]=v[1];
        f32x2 s1; s1[0]=v[2]; s1[1]=v[3];
        __hip_atomic_store(&g_Vb[np][dir][row_s][vb_i],
          __builtin_bit_cast(unsigned long long, s0), __ATOMIC_RELAXED, __HIP_MEMORY_SCOPE_AGENT);
        __hip_atomic_store(&g_Vb[np][dir][row_s][vb_i + 1],
          __builtin_bit_cast(unsigned long long, s1), __ATOMIC_RELAXED, __HIP_MEMORY_SCOPE_AGENT);
      }
    }
    // x slices (read-only, cached)
    const f32x4 xa0 = *(const f32x4*)&g_xr[row0][pos][g*8];
    const f32x4 xb0 = *(const f32x4*)&g_xr[row0][pos][g*8 + 4];
    const f32x4 xa1 = *(const f32x4*)&g_xr[row0 + 16][pos][g*8];
    const f32x4 xb1 = *(const f32x4*)&g_xr[row0 + 16][pos][g*8 + 4];

    __syncthreads();   // Vl ready (and Bl on s==0)

    f32x4 ac0[4] = { z4(), z4(), z4(), z4() };
    f32x4 ac1[4] = { z4(), z4(), z4(), z4() };
    #pragma unroll 4
    for (int ks = 0; ks < KS; ks++){
      const float va = Vl[ks*132 + ml0];
      const float vb = Vl[ks*132 + ml0 + 16];
      short8 b0 = Bw[(ks*8 + 0)*64];
      short8 b1 = Bw[(ks*8 + 1)*64];
      short8 b2 = Bw[(ks*8 + 2)*64];
      short8 b3 = Bw[(ks*8 + 3)*64];
      const short8 a0 = genA(va, xa0, xb0);
      ac0[0] = __builtin_amdgcn_mfma_f32_16x16x32_bf16(a0, b0, ac0[0], 0, 0, 0);
      ac0[1] = __builtin_amdgcn_mfma_f32_16x16x32_bf16(a0, b1, ac0[1], 0, 0, 0);
      ac0[2] = __builtin_amdgcn_mfma_f32_16x16x32_bf16(a0, b2, ac0[2], 0, 0, 0);
      ac0[3] = __builtin_amdgcn_mfma_f32_16x16x32_bf16(a0, b3, ac0[3], 0, 0, 0);
      const short8 a1 = genA(vb, xa1, xb1);
      ac1[0] = __builtin_amdgcn_mfma_f32_16x16x32_bf16(a1, b0, ac1[0], 0, 0, 0);
      ac1[1] = __builtin_amdgcn_mfma_f32_16x16x32_bf16(a1, b1, ac1[1], 0, 0, 0);
      ac1[2] = __builtin_amdgcn_mfma_f32_16x16x32_bf16(a1, b2, ac1[2], 0, 0, 0);
      ac1[3] = __builtin_amdgcn_mfma_f32_16x16x32_bf16(a1, b3, ac1[3], 0, 0, 0);
    }

    // ---- write bf16 partials: 8B device-scope stores (ni's are n-consecutive) ----
    {
      const int row_o0 = bt*128 + wm*32 + ((lane >> 4) << 2);
      const int pc_o = nt*32 + wn*16 + (lane & 15);   // u64 index in Pc row
      #pragma unroll
      for (int rr = 0; rr < 4; rr++){
        u16x4 p0, p1;
        #pragma unroll
        for (int ni = 0; ni < 4; ni++){
          p0[ni] = f2bf(ac0[ni][rr]);
          p1[ni] = f2bf(ac1[ni][rr]);
        }
        __hip_atomic_store(&g_Pc[np][kq][dir][row_o0 + rr][pc_o],
          __builtin_bit_cast(unsigned long long, p0), __ATOMIC_RELAXED, __HIP_MEMORY_SCOPE_AGENT);
        __hip_atomic_store(&g_Pc[np][kq][dir][row_o0 + 16 + rr][pc_o],
          __builtin_bit_cast(unsigned long long, p1), __ATOMIC_RELAXED, __HIP_MEMORY_SCOPE_AGENT);
      }
    }

    // ---- fenceless group barrier (stores drained by pre-barrier vmcnt) ----
    __syncthreads();
    if (t == 0){
      __hip_atomic_fetch_add(&g_sync[grp][0], 1u, __ATOMIC_RELAXED, __HIP_MEMORY_SCOPE_AGENT);
      const unsigned int target = 32u * (unsigned)(s + 1);
      while (__hip_atomic_load(&g_sync[grp][0], __ATOMIC_RELAXED, __HIP_MEMORY_SCOPE_AGENT) < target)
        __builtin_amdgcn_s_sleep(2);
    }
    __syncthreads();
  }
}

// ---- final boundary vectors; L split hi/lo bf16 ----
__global__ void k_lr(){
  const int id = blockIdx.x*256 + threadIdx.x;  // 1024 blocks
  const int n = id & 255;
  const int b = (id >> 8) & 511;
  const int dir = id >> 17;
  float s = ((const float*)&g_Vb[0][dir][b][0])[n];
  #pragma unroll
  for (int q = 0; q < NQ2; q++)
    s += b2f(((const unsigned short*)&g_Pc[0][q][dir][b][0])[n]);
  if (dir == 0){
    const unsigned int u = __float_as_uint(s);
    g_Lh[b][n] = (short)(u >> 16);
    const float rr = s - __uint_as_float(u & 0xFFFF0000u);
    g_Ll[b][n] = (short)(__float_as_uint(rr) >> 16);
  } else {
    g_Rf[b][n] = s;
  }
}

// ---- T[b,(o,e)] = sum_d L[b,d] * oc[d,(o,e)] ----
__launch_bounds__(512, 1)
__global__ void k_gemm1(){
  const int bt = blockIdx.x >> 5;
  const int nt = blockIdx.x & 31;
  const int t = threadIdx.x, lane = t & 63;
  const int w = t >> 6, wm = w >> 2, wn = w & 3;
  f32x4 acc[4][2];
  #pragma unroll
  for (int i = 0; i < 4; i++)
    #pragma unroll
    for (int j = 0; j < 2; j++) acc[i][j] = z4();
  #pragma unroll
  for (int ks = 0; ks < 8; ks++){
    short8 bfr[2];
    #pragma unroll
    for (int ni = 0; ni < 2; ni++)
      bfr[ni] = *(const short8*)&g_BpreOC[ks][nt*8 + wn*2 + ni][lane][0];
    const int k0 = ks*32 + (lane >> 4)*8;
    #pragma unroll
    for (int mi = 0; mi < 4; mi++){
      const int bm = bt*128 + wm*64 + mi*16 + (lane & 15);
      const short8 ah = *(const short8*)&g_Lh[bm][k0];
      const short8 al = *(const short8*)&g_Ll[bm][k0];
      #pragma unroll
      for (int ni = 0; ni < 2; ni++){
        acc[mi][ni] = __builtin_amdgcn_mfma_f32_16x16x32_bf16(ah, bfr[ni], acc[mi][ni], 0, 0, 0);
        acc[mi][ni] = __builtin_amdgcn_mfma_f32_16x16x32_bf16(al, bfr[ni], acc[mi][ni], 0, 0, 0);
      }
    }
  }
  #pragma unroll
  for (int mi = 0; mi < 4; mi++){
    const int row0 = bt*128 + wm*64 + mi*16 + ((lane >> 4) << 2);
    #pragma unroll
    for (int ni = 0; ni < 2; ni++){
      const int n = nt*128 + wn*32 + ni*16 + (lane & 15);
      #pragma unroll
      for (int r = 0; r < 4; r++) g_T[row0 + r][n] = acc[mi][ni][r];
    }
  }
}

// ---- out[b,o] = sum_e T[b,(o,e)] * R[b,e] ----
__global__ void k_out(float* __restrict__ out){
  const int b0 = blockIdx.x * 8;    // 64 blocks
  __shared__ float Rl[8][256];
  const int t = threadIdx.x;
  for (int i = t; i < 2048; i += 256)
    Rl[i >> 8][i & 255] = g_Rf[b0 + (i >> 8)][i & 255];
  __syncthreads();
  const int bl = t >> 5;
  const int o  = (t >> 1) & 15;
  const int eh = t & 1;
  const float* Trow = &g_T[b0 + bl][o*256 + eh*128];
  const float* Rr = &Rl[bl][eh*128];
  float acc = 0.f;
  #pragma unroll 8
  for (int e4 = 0; e4 < 32; e4++){
    const f32x4 tv = *(const f32x4*)(Trow + e4*4);
    const f32x4 rv = *(const f32x4*)(Rr + e4*4);
    acc += tv[0]*rv[0] + tv[1]*rv[1] + tv[2]*rv[2] + tv[3]*rv[3];
  }
  acc += __shfl_xor(acc, 1);
  if (eh == 0) out[(b0 + bl)*16 + o] = acc;
}

extern "C" void kernel_launch(void* const* d_in, const int* in_sizes, int n_in,
                              void* d_out, int out_size, void* d_ws, size_t ws_size,
                              hipStream_t stream){
  const float* inputs = (const float*)d_in[0];
  const float* core   = (const float*)d_in[1];
  const float* alpha  = (const float*)d_in[2];
  const float* omega  = (const float*)d_in[3];
  const float* oc     = (const float*)d_in[4];
  float* out = (float*)d_out;
  (void)in_sizes; (void)n_in; (void)out_size; (void)d_ws; (void)ws_size;

  k_coreT <<<dim3(2112), dim3(256), 0, stream>>>(core);
  k_bf    <<<dim3(1024), dim3(512), 0, stream>>>(core);
  k_bpreoc<<<dim3(512),  dim3(256), 0, stream>>>(oc);
  k_xr    <<<dim3(2048), dim3(256), 0, stream>>>(inputs);
  k_init  <<<dim3(256),  dim3(512), 0, stream>>>(alpha, omega);

  const unsigned int ldsBytes = 131072 + 16*132*4;  // 139520
  (void)hipFuncSetAttribute((const void*)k_chain,
                      hipFuncAttributeMaxDynamicSharedMemorySize, (int)ldsBytes);
  int nsteps = 64;
  void* args[] = { &nsteps };
  (void)hipLaunchCooperativeKernel((const void*)k_chain, dim3(256), dim3(512),
                             args, ldsBytes, stream);

  k_lr    <<<dim3(1024), dim3(256), 0, stream>>>();
  k_gemm1 <<<dim3(128),  dim3(512), 0, stream>>>();
  k_out   <<<dim3(64),   dim3(256), 0, stream>>>(out);
}

// Round 9
// 661.909 us; speedup vs baseline: 2.9392x; 1.0776x over previous
//
#include <hip/hip_runtime.h>
#include <hip/hip_bf16.h>
#include <stdint.h>
#include <stddef.h>

typedef __attribute__((ext_vector_type(8))) short short8;
typedef __attribute__((ext_vector_type(4))) float f32x4;
typedef __attribute__((ext_vector_type(2))) float f32x2;
typedef __attribute__((ext_vector_type(4))) unsigned int u32x4;
typedef __attribute__((ext_vector_type(4))) unsigned short u16x4;
typedef __attribute__((ext_vector_type(2))) unsigned short u16x2;

#define NB 512
#define NL 128
#define ND 256
#define NO 16
#define NQ2 16     // K-split planes (d-chunks of 16)
#define KS 16      // MFMA k-steps per chunk

// ---- static device scratch ----
// u64-typed so 8B __hip_atomic_* ops have provable natural alignment.
__device__ __attribute__((aligned(16))) unsigned long long g_Vb[2][2][NB][ND/2];      // fp32 carrier
__device__ __attribute__((aligned(16))) unsigned long long g_Pc[2][NQ2][2][NB][ND/4]; // bf16 partials
__device__ __attribute__((aligned(16))) short g_Bf[2][NQ2][2][KS][8][64][8];          // frag-major B (bf16)
__device__ __attribute__((aligned(16))) float g_coreT[ND][33][ND];                    // core^T
__device__ __attribute__((aligned(16))) float g_xr[NB][NL][32];                       // packed x (f32)
__device__ __attribute__((aligned(16))) short g_BpreOC[8][256][64][8];
__device__ __attribute__((aligned(16))) float g_Rf[NB][ND];
__device__ __attribute__((aligned(16))) short g_Lh[NB][ND];
__device__ __attribute__((aligned(16))) short g_Ll[NB][ND];
__device__ __attribute__((aligned(16))) float g_T[NB][NO*ND];
__device__ __attribute__((aligned(256))) unsigned int g_sync[8][64];  // padded counters

__device__ inline unsigned short bf16_rne(float f){
  unsigned int u = __float_as_uint(f);
  return (unsigned short)((u + 0x7FFFu + ((u >> 16) & 1u)) >> 16);
}
__device__ inline float b2f(unsigned short u){
  return __uint_as_float((unsigned int)u << 16);
}
__device__ inline unsigned short f2bf(float f){
  __hip_bfloat16 h = __float2bfloat16(f);
  unsigned short u; __builtin_memcpy(&u, &h, 2); return u;
}
__device__ inline unsigned int pk2(float a, float b){
  __hip_bfloat162 h = __float22bfloat162_rn(make_float2(a, b));
  unsigned int u; __builtin_memcpy(&u, &h, 4); return u;
}
__device__ inline f32x4 z4(){ f32x4 v; v[0]=0.f; v[1]=0.f; v[2]=0.f; v[3]=0.f; return v; }

// A-fragment: bf16(vm * x[i]) for i=0..7 (round-5 proven numerics)
__device__ inline short8 genA(float vm, const f32x4 xa, const f32x4 xb){
  u32x4 u;
  u[0] = pk2(vm*xa[0], vm*xa[1]);
  u[1] = pk2(vm*xa[2], vm*xa[3]);
  u[2] = pk2(vm*xb[0], vm*xb[1]);
  u[3] = pk2(vm*xb[2], vm*xb[3]);
  return __builtin_bit_cast(short8, u);
}

// ---- core^T (tiled, coalesced): g_coreT[e][f][d] = core[d][f][e] ----
__global__ void k_coreT(const float* __restrict__ core){
  const int bid = blockIdx.x;            // 2112
  const int f  = bid % 33;
  const int dt = (bid / 33) & 7;
  const int et = bid / 264;
  __shared__ float tile[32][33];
  const int j  = threadIdx.x & 31;
  const int i0 = threadIdx.x >> 5;
  #pragma unroll
  for (int ii = 0; ii < 4; ii++){
    const int i = i0*4 + ii;
    tile[i][j] = core[((size_t)(dt*32 + i)*33 + f)*256 + et*32 + j];
  }
  __syncthreads();
  #pragma unroll
  for (int ii = 0; ii < 4; ii++){
    const int i = i0*4 + ii;
    g_coreT[et*32 + i][f][dt*32 + j] = tile[j][i];
  }
}

// ---- fragment-major bf16 B, both dirs; ni-interleaved column permutation ----
// fragment nf holds logical column (nf&~3)*16 + (l&15)*4 + (nf&3)
__global__ void k_bf(const float* __restrict__ core){
  const int id = blockIdx.x*512 + threadIdx.x;   // 1024 blocks
  const int l   = id & 63;
  const int nf  = (id >> 6) & 7;
  const int ks  = (id >> 9) & 15;
  const int nt  = (id >> 13) & 1;
  const int kq  = (id >> 14) & 15;
  const int dir = id >> 18;
  const float* src = dir ? &g_coreT[0][0][0] : core;
  const int n_g = nt*128 + (nf >> 2)*64 + (l & 15)*4 + (nf & 3);
  const int dl  = kq*16 + ks;
  short8 v;
  #pragma unroll
  for (int i = 0; i < 8; i++){
    const int f = (l >> 4)*8 + i + 1;
    v[i] = (short)bf16_rne(src[((size_t)dl*33 + f)*256 + n_g]);
  }
  *(short8*)&g_Bf[dir][kq][nt][ks][nf][l][0] = v;
}

// ---- fragment-major output_core ----
__global__ void k_bpreoc(const float* __restrict__ oc){
  const int id = blockIdx.x*256 + threadIdx.x;  // 512 blocks
  const int l = id & 63;
  const int nfrag = (id >> 6) & 255;
  const int ks = id >> 14;
  const int g = l >> 4;
  short8 v;
  #pragma unroll
  for (int i = 0; i < 8; i++){
    const int d = ks*32 + g*8 + i;
    v[i] = (short)bf16_rne(oc[(size_t)d*4096 + nfrag*16 + (l & 15)]);
  }
  *(short8*)&g_BpreOC[ks][nfrag][l][0] = v;
}

// ---- repack inputs, dropping bias channel ----
__global__ void k_xr(const float* __restrict__ inputs){
  const int id = blockIdx.x*256 + threadIdx.x;  // 2048 blocks
  const int j = id & 7;
  const int pos = (id >> 3) & 127;
  const int b = id >> 10;
  const float* src = inputs + ((size_t)b*128 + pos)*33 + 1 + j*4;
  f32x4 v; v[0]=src[0]; v[1]=src[1]; v[2]=src[2]; v[3]=src[3];
  *(f32x4*)&g_xr[b][pos][j*4] = v;
}

// ---- init: Vb[0] = alpha/omega, sync = 0 ----
__global__ void k_init(const float* __restrict__ alpha, const float* __restrict__ omega){
  const int id = blockIdx.x*512 + threadIdx.x;  // 256 blocks -> 131072 u64 elems
  const int n2 = id & 127;
  const int b = (id >> 7) & 511;
  const int dir = id >> 16;
  const float* src = dir ? omega : alpha;
  f32x2 v; v[0] = src[n2*2]; v[1] = src[n2*2 + 1];
  g_Vb[0][dir][b][n2] = __builtin_bit_cast(unsigned long long, v);
  if (id < 512) ((unsigned int*)g_sync)[id] = 0;
}

// ---- persistent chain kernel: 256 blocks x 1024 thr (16 waves = 4/SIMD) ----
__global__ void __launch_bounds__(1024, 4) k_chain(int nsteps){
  extern __shared__ char lds[];
  short* Bl = (short*)lds;                      // [16 ks][8 nf][64][8] = 128 KB
  float* Vl = (float*)(lds + 131072);           // [16][132]

  const int bid = blockIdx.x;                   // 256
  const int dir = bid & 1;
  const int bt  = (bid >> 1) & 3;
  const int j   = bid >> 3;
  const int kq  = j & 15;
  const int nt  = j >> 4;                       // 0..1
  const int grp = bid & 7;                      // (dir,bt): 32 blocks, XCD-local

  const int t = threadIdx.x;
  const int lane = t & 63, w = t >> 6;          // 16 waves
  const int wm = w & 7, wn = w >> 3;            // wave tile 16m x 64n

  // one-time: B slice -> LDS (8 iters x 1024 thr x 16 B = exactly 128 KB)
  {
    const short8* src = (const short8*)&g_Bf[dir][kq][nt][0][0][0][0];
    short8* dst = (short8*)Bl;
    #pragma unroll
    for (int it = 0; it < 8; it++)
      dst[it*1024 + t] = src[it*1024 + t];
  }

  const int m_s   = t >> 3;                     // staging row 0..127
  const int dg    = t & 7;                      // 2 d's each
  const int row_s = bt*128 + m_s;
  const int vbq_i = kq*8 + dg;                  // u64 index into Vb row (2 floats)
  const int pcw_i = kq*8 + dg;                  // u32 index into Pc row (2 bf16)
  const int ml0   = wm*16 + (lane & 15);
  const int row0  = bt*128 + ml0;
  const int g     = lane >> 4;
  const short8* Bw = ((const short8*)Bl) + (wn*4)*64 + lane;

  for (int s = 0; s < nsteps; s++){
    const int pp = s & 1, np = pp ^ 1;
    const int pos = dir ? (127 - s) : s;

    // ---- staging: V(2 d's) = Vb + sum of 16 bf16 partials (agent loads) ----
    {
      unsigned long long vb = __hip_atomic_load(&g_Vb[pp][dir][row_s][vbq_i],
        __ATOMIC_RELAXED, __HIP_MEMORY_SCOPE_AGENT);
      f32x2 v = __builtin_bit_cast(f32x2, vb);
      if (s > 0){
        unsigned int cs[NQ2];
        const unsigned int* pc =
          (const unsigned int*)&g_Pc[pp][0][dir][row_s][0] + pcw_i;
        #pragma unroll
        for (int q = 0; q < NQ2; q++)
          cs[q] = __hip_atomic_load(pc + (size_t)q * (2*NB*(ND/2)),
            __ATOMIC_RELAXED, __HIP_MEMORY_SCOPE_AGENT);
        #pragma unroll
        for (int q = 0; q < NQ2; q++){
          u16x2 c = __builtin_bit_cast(u16x2, cs[q]);
          v[0] += b2f(c[0]); v[1] += b2f(c[1]);
        }
      }
      Vl[(dg*2 + 0)*132 + m_s] = v[0];
      Vl[(dg*2 + 1)*132 + m_s] = v[1];
      if (nt == 0)
        __hip_atomic_store(&g_Vb[np][dir][row_s][vbq_i],
          __builtin_bit_cast(unsigned long long, v),
          __ATOMIC_RELAXED, __HIP_MEMORY_SCOPE_AGENT);
    }
    // x slices (read-only, cached)
    const f32x4 xa = *(const f32x4*)&g_xr[row0][pos][g*8];
    const f32x4 xb = *(const f32x4*)&g_xr[row0][pos][g*8 + 4];

    __syncthreads();   // Vl ready (and Bl on s==0)

    f32x4 ac[4] = { z4(), z4(), z4(), z4() };
    #pragma unroll 4
    for (int ks = 0; ks < KS; ks++){
      const float va = Vl[ks*132 + ml0];
      short8 b0 = Bw[(ks*8 + 0)*64];
      short8 b1 = Bw[(ks*8 + 1)*64];
      short8 b2 = Bw[(ks*8 + 2)*64];
      short8 b3 = Bw[(ks*8 + 3)*64];
      const short8 a = genA(va, xa, xb);
      ac[0] = __builtin_amdgcn_mfma_f32_16x16x32_bf16(a, b0, ac[0], 0, 0, 0);
      ac[1] = __builtin_amdgcn_mfma_f32_16x16x32_bf16(a, b1, ac[1], 0, 0, 0);
      ac[2] = __builtin_amdgcn_mfma_f32_16x16x32_bf16(a, b2, ac[2], 0, 0, 0);
      ac[3] = __builtin_amdgcn_mfma_f32_16x16x32_bf16(a, b3, ac[3], 0, 0, 0);
    }

    // ---- write bf16 partials: u64 agent stores (ni's are n-consecutive) ----
    {
      const int row_o = bt*128 + wm*16 + ((lane >> 4) << 2);
      const int pc_o = nt*32 + wn*16 + (lane & 15);   // u64 col index
      #pragma unroll
      for (int rr = 0; rr < 4; rr++){
        u16x4 p;
        #pragma unroll
        for (int ni = 0; ni < 4; ni++) p[ni] = f2bf(ac[ni][rr]);
        __hip_atomic_store(&g_Pc[np][kq][dir][row_o + rr][pc_o],
          __builtin_bit_cast(unsigned long long, p),
          __ATOMIC_RELAXED, __HIP_MEMORY_SCOPE_AGENT);
      }
    }

    // ---- fenceless group barrier (stores drained by pre-barrier vmcnt) ----
    __syncthreads();
    if (t == 0){
      __hip_atomic_fetch_add(&g_sync[grp][0], 1u, __ATOMIC_RELAXED, __HIP_MEMORY_SCOPE_AGENT);
      const unsigned int target = 32u * (unsigned)(s + 1);
      while (__hip_atomic_load(&g_sync[grp][0], __ATOMIC_RELAXED, __HIP_MEMORY_SCOPE_AGENT) < target)
        __builtin_amdgcn_s_sleep(2);
    }
    __syncthreads();
  }
}

// ---- final boundary vectors; L split hi/lo bf16 ----
__global__ void k_lr(){
  const int id = blockIdx.x*256 + threadIdx.x;  // 1024 blocks
  const int n = id & 255;
  const int b = (id >> 8) & 511;
  const int dir = id >> 17;
  float s = ((const float*)&g_Vb[0][dir][b][0])[n];
  #pragma unroll
  for (int q = 0; q < NQ2; q++)
    s += b2f(((const unsigned short*)&g_Pc[0][q][dir][b][0])[n]);
  if (dir == 0){
    const unsigned int u = __float_as_uint(s);
    g_Lh[b][n] = (short)(u >> 16);
    const float rr = s - __uint_as_float(u & 0xFFFF0000u);
    g_Ll[b][n] = (short)(__float_as_uint(rr) >> 16);
  } else {
    g_Rf[b][n] = s;
  }
}

// ---- T[b,(o,e)] = sum_d L[b,d] * oc[d,(o,e)] ----
__launch_bounds__(512, 1)
__global__ void k_gemm1(){
  const int bt = blockIdx.x >> 5;
  const int nt = blockIdx.x & 31;
  const int t = threadIdx.x, lane = t & 63;
  const int w = t >> 6, wm = w >> 2, wn = w & 3;
  f32x4 acc[4][2];
  #pragma unroll
  for (int i = 0; i < 4; i++)
    #pragma unroll
    for (int jj = 0; jj < 2; jj++) acc[i][jj] = z4();
  #pragma unroll
  for (int ks = 0; ks < 8; ks++){
    short8 bfr[2];
    #pragma unroll
    for (int ni = 0; ni < 2; ni++)
      bfr[ni] = *(const short8*)&g_BpreOC[ks][nt*8 + wn*2 + ni][lane][0];
    const int k0 = ks*32 + (lane >> 4)*8;
    #pragma unroll
    for (int mi = 0; mi < 4; mi++){
      const int bm = bt*128 + wm*64 + mi*16 + (lane & 15);
      const short8 ah = *(const short8*)&g_Lh[bm][k0];
      const short8 al = *(const short8*)&g_Ll[bm][k0];
      #pragma unroll
      for (int ni = 0; ni < 2; ni++){
        acc[mi][ni] = __builtin_amdgcn_mfma_f32_16x16x32_bf16(ah, bfr[ni], acc[mi][ni], 0, 0, 0);
        acc[mi][ni] = __builtin_amdgcn_mfma_f32_16x16x32_bf16(al, bfr[ni], acc[mi][ni], 0, 0, 0);
      }
    }
  }
  #pragma unroll
  for (int mi = 0; mi < 4; mi++){
    const int row0 = bt*128 + wm*64 + mi*16 + ((lane >> 4) << 2);
    #pragma unroll
    for (int ni = 0; ni < 2; ni++){
      const int n = nt*128 + wn*32 + ni*16 + (lane & 15);
      #pragma unroll
      for (int r = 0; r < 4; r++) g_T[row0 + r][n] = acc[mi][ni][r];
    }
  }
}

// ---- out[b,o] = sum_e T[b,(o,e)] * R[b,e] ----
__global__ void k_out(float* __restrict__ out){
  const int b0 = blockIdx.x * 8;    // 64 blocks
  __shared__ float Rl[8][256];
  const int t = threadIdx.x;
  for (int i = t; i < 2048; i += 256)
    Rl[i >> 8][i & 255] = g_Rf[b0 + (i >> 8)][i & 255];
  __syncthreads();
  const int bl = t >> 5;
  const int o  = (t >> 1) & 15;
  const int eh = t & 1;
  const float* Trow = &g_T[b0 + bl][o*256 + eh*128];
  const float* Rr = &Rl[bl][eh*128];
  float acc = 0.f;
  #pragma unroll 8
  for (int e4 = 0; e4 < 32; e4++){
    const f32x4 tv = *(const f32x4*)(Trow + e4*4);
    const f32x4 rv = *(const f32x4*)(Rr + e4*4);
    acc += tv[0]*rv[0] + tv[1]*rv[1] + tv[2]*rv[2] + tv[3]*rv[3];
  }
  acc += __shfl_xor(acc, 1);
  if (eh == 0) out[(b0 + bl)*16 + o] = acc;
}

extern "C" void kernel_launch(void* const* d_in, const int* in_sizes, int n_in,
                              void* d_out, int out_size, void* d_ws, size_t ws_size,
                              hipStream_t stream){
  const float* inputs = (const float*)d_in[0];
  const float* core   = (const float*)d_in[1];
  const float* alpha  = (const float*)d_in[2];
  const float* omega  = (const float*)d_in[3];
  const float* oc     = (const float*)d_in[4];
  float* out = (float*)d_out;
  (void)in_sizes; (void)n_in; (void)out_size; (void)d_ws; (void)ws_size;

  k_coreT <<<dim3(2112), dim3(256), 0, stream>>>(core);
  k_bf    <<<dim3(1024), dim3(512), 0, stream>>>(core);
  k_bpreoc<<<dim3(512),  dim3(256), 0, stream>>>(oc);
  k_xr    <<<dim3(2048), dim3(256), 0, stream>>>(inputs);
  k_init  <<<dim3(256),  dim3(512), 0, stream>>>(alpha, omega);

  const unsigned int ldsBytes = 131072 + 16*132*4;  // 139520
  (void)hipFuncSetAttribute((const void*)k_chain,
                      hipFuncAttributeMaxDynamicSharedMemorySize, (int)ldsBytes);
  int nsteps = 64;
  void* args[] = { &nsteps };
  hipError_t ce = hipLaunchCooperativeKernel((const void*)k_chain, dim3(256), dim3(1024),
                                             args, ldsBytes, stream);
  if (ce != hipSuccess){
    // fallback: normal launch (256 blocks @ 1/CU are de-facto co-resident)
    k_chain<<<dim3(256), dim3(1024), ldsBytes, stream>>>(64);
  }

  k_lr    <<<dim3(1024), dim3(256), 0, stream>>>();
  k_gemm1 <<<dim3(128),  dim3(512), 0, stream>>>();
  k_out   <<<dim3(64),   dim3(256), 0, stream>>>(out);
}